// Round 2
// baseline (355.378 us; speedup 1.0000x reference)
//
#include <hip/hip_runtime.h>
#include <math.h>

#define B_ 64
#define N_ 200
#define P_ 400
#define T_ 1200
#define STRIDE_ 25
#define EPS_ 1e-9f
#define KPAD 224

// ws layout (float offsets)
#define OFF_NPATT  0            // [N_][P_] f32 transposed normalized patterns (80000)
#define OFF_NPB16  80000        // [P_][KPAD] bf16 normalized patterns (89600 u16 = 44800 f32)
#define OFF_KEYVAL 124800       // [P_][4]
#define OFF_KEYIDX 126400       // [P_][4] int
#define OFF_PES    128000       // [B_][P_]
#define OFF_NORM   153600
#define OFF_ORTH   153601

typedef float f4v __attribute__((ext_vector_type(4)));
typedef short s8v __attribute__((ext_vector_type(8)));
typedef short s4v __attribute__((ext_vector_type(4)));

__device__ inline unsigned short f2bf(float f) {
    union { float f; unsigned u; } v; v.f = f;
    unsigned r = v.u + 0x7FFFu + ((v.u >> 16) & 1u);
    return (unsigned short)(r >> 16);
}
__device__ inline unsigned okey(float f) {
    unsigned u = __float_as_uint(f);
    return (u & 0x80000000u) ? ~u : (u | 0x80000000u);
}
__device__ inline float dekey(unsigned k) {
    unsigned u = (k & 0x80000000u) ? (k & 0x7fffffffu) : ~k;
    return __uint_as_float(u);
}

// ---------------- pattern preprocessing: normalize rows, top-3, norm scalar ----
__global__ __launch_bounds__(64) void pat_kernel(const float* __restrict__ patterns,
                                                 float* __restrict__ ws) {
    int p = blockIdx.x;
    int lane = threadIdx.x;

    float v0 = patterns[p * N_ + lane];
    float v1 = patterns[p * N_ + lane + 64];
    float v2 = patterns[p * N_ + lane + 128];
    float v3 = (lane < 8) ? patterns[p * N_ + lane + 192] : 0.0f;

    float ss = v0 * v0 + v1 * v1 + v2 * v2 + v3 * v3;
    for (int off = 32; off; off >>= 1) ss += __shfl_down(ss, off);
    ss = __shfl(ss, 0);

    float rn = 1.0f / sqrtf(ss + EPS_);
    float s0 = v0 * rn, s1 = v1 * rn, s2 = v2 * rn, s3 = v3 * rn;

    float* npatT = ws + OFF_NPATT;
    npatT[(lane) * P_ + p] = s0;
    npatT[(lane + 64) * P_ + p] = s1;
    npatT[(lane + 128) * P_ + p] = s2;
    if (lane < 8) npatT[(lane + 192) * P_ + p] = s3;

    // bf16 row-major copy, K padded with zeros
    unsigned short* npb = (unsigned short*)(ws + OFF_NPB16);
    npb[p * KPAD + lane] = f2bf(s0);
    npb[p * KPAD + lane + 64] = f2bf(s1);
    npb[p * KPAD + lane + 128] = f2bf(s2);
    if (lane < 8) npb[p * KPAD + lane + 192] = f2bf(s3);
    if (lane < 24) npb[p * KPAD + 200 + lane] = 0;

    float a0 = fabsf(s0), a1 = fabsf(s1), a2 = fabsf(s2);
    float a3 = fabsf(s3);

    int ch0 = -1, ch1 = -1, ch2 = -1;
    float cs0 = 0.f, cs1 = 0.f, cs2 = 0.f;

    for (int r = 0; r < 3; r++) {
        float bv = -1.0f;
        int bi = 1 << 30;
        {
            int n = lane;
            bool sk = (n == ch0) || (n == ch1) || (n == ch2);
            if (!sk && a0 > bv) { bv = a0; bi = n; }
        }
        {
            int n = lane + 64;
            bool sk = (n == ch0) || (n == ch1) || (n == ch2);
            if (!sk && (a1 > bv || (a1 == bv && n < bi))) { bv = a1; bi = n; }
        }
        {
            int n = lane + 128;
            bool sk = (n == ch0) || (n == ch1) || (n == ch2);
            if (!sk && (a2 > bv || (a2 == bv && n < bi))) { bv = a2; bi = n; }
        }
        if (lane < 8) {
            int n = lane + 192;
            bool sk = (n == ch0) || (n == ch1) || (n == ch2);
            if (!sk && (a3 > bv || (a3 == bv && n < bi))) { bv = a3; bi = n; }
        }
        for (int off = 32; off; off >>= 1) {
            float ov = __shfl_down(bv, off);
            int oi = __shfl_down(bi, off);
            if (ov > bv || (ov == bv && oi < bi)) { bv = ov; bi = oi; }
        }
        bi = __shfl(bi, 0);
        int slot = bi >> 6, src = bi & 63;
        float mine = (slot == 0) ? s0 : (slot == 1) ? s1 : (slot == 2) ? s2 : s3;
        float sval = __shfl(mine, src);
        if (r == 0) { ch0 = bi; cs0 = sval; }
        else if (r == 1) { ch1 = bi; cs1 = sval; }
        else { ch2 = bi; cs2 = sval; }
    }

    if (lane == 0) {
        float* keyval = ws + OFF_KEYVAL;
        int* keyidx = (int*)(ws + OFF_KEYIDX);
        keyval[p * 4 + 0] = cs0; keyval[p * 4 + 1] = cs1; keyval[p * 4 + 2] = cs2;
        keyidx[p * 4 + 0] = ch0; keyidx[p * 4 + 1] = ch1; keyidx[p * 4 + 2] = ch2;
        float lenp = sqrtf(ss) * rn;
        float lentopp = sqrtf(cs0 * cs0 + cs1 * cs1 + cs2 * cs2);
        float d = 1.0f - lentopp / lenp;
        atomicAdd(ws + OFF_NORM, d * d * (1.0f / (float)P_));
    }
}

// ---------------- orth regularizer -----------------------------------------
__global__ __launch_bounds__(256) void orth_kernel(float* __restrict__ ws) {
    __shared__ float rowi[N_];
    __shared__ float red[256];
    const float* npatT = ws + OFF_NPATT;
    int i = blockIdx.x;
    for (int k = threadIdx.x; k < N_; k += 256) rowi[k] = npatT[k * P_ + i];
    __syncthreads();

    float partial = 0.0f;
    for (int j = threadIdx.x; j < P_; j += 256) {
        if (j == i) continue;
        float s = 0.0f;
        for (int k = 0; k < N_; k++) s += rowi[k] * npatT[k * P_ + j];
        float t = (fabsf(s) - 0.3f) * (1.0f / 0.70001f);
        if (t > 0.0f) partial += t * t;
    }
    red[threadIdx.x] = partial;
    __syncthreads();
    for (int sft = 128; sft; sft >>= 1) {
        if (threadIdx.x < sft) red[threadIdx.x] += red[threadIdx.x + sft];
        __syncthreads();
    }
    if (threadIdx.x == 0)
        atomicAdd(ws + OFF_ORTH, red[0] * (1.0f / ((float)P_ * (float)P_)));
}

// ---------------- MFMA GEMM + fused window pooling -> PES -------------------
// grid (5 pblocks, 3 mblocks, 64 b); block 320 thr = 5 waves.
// Tile: M=400 frames (16 windows exactly), N=80 patterns, K=200 (7 chunks of 32).
__global__ __launch_bounds__(320, 3) void mfma_kernel(const float* __restrict__ x,
                                                      const int* __restrict__ length,
                                                      const float* __restrict__ ws,
                                                      float* __restrict__ pes) {
    __shared__ short ldsA[400 * 36];       // [frame][k] bf16, stride 36
    __shared__ short ldsB[80 * 40];        // [pat][k] bf16, stride 40
    __shared__ unsigned pool[16 * 80];     // ordered-uint max pool
    __shared__ float rnacc[400];           // frame sumsq accum (f32, raw x)
    __shared__ float rnorm[400];
    __shared__ float psum[80];

    const int tid = threadIdx.x;
    const int pb = blockIdx.x;
    const int mb = blockIdx.y;
    const int b  = blockIdx.z;

    for (int i = tid; i < 400; i += 320) rnacc[i] = 0.f;
    for (int i = tid; i < 1280; i += 320) pool[i] = 0u;   // key 0 == -inf
    if (tid < 80) psum[tid] = 0.f;

    f4v acc[5][5];
#pragma unroll
    for (int mi = 0; mi < 5; ++mi)
#pragma unroll
        for (int ni = 0; ni < 5; ++ni) acc[mi][ni] = (f4v){0.f, 0.f, 0.f, 0.f};

    const int wv = tid >> 6;
    const int lane = tid & 63;
    const int l15 = lane & 15, kg = lane >> 4;

    const int cp = tid / 20, jt = tid % 20;     // A staging: chan-pair, frame-group

    const unsigned short* npb = (const unsigned short*)(ws + OFF_NPB16) + (size_t)(pb * 80) * KPAD;
    const float* xbase = x + (size_t)b * N_ * T_ + (size_t)mb * 400;

    for (int c = 0; c < 7; ++c) {
        __syncthreads();
        // ---- stage B chunk: 80 pats x 32 k
        {
            int p = tid >> 2, kh = tid & 3;
            s8v bv = *(const s8v*)(npb + (size_t)p * KPAD + c * 32 + kh * 8);
            *(s8v*)(&ldsB[p * 40 + kh * 8]) = bv;
        }
        // ---- stage A chunk (transpose f32->bf16 pairs) + frame sumsq
        {
            int c0 = c * 32 + cp * 2;
            const float* xr0 = xbase + (size_t)c0 * T_;
            const float* xr1 = xr0 + T_;
            bool ok0 = (c0 < N_), ok1 = (c0 + 1 < N_);
            unsigned* ldsA32 = (unsigned*)ldsA;
#pragma unroll
            for (int i = 0; i < 5; ++i) {
                int fp = jt + 20 * i;          // float4 index; frames 4fp..4fp+3
                float4 a4 = ok0 ? *(const float4*)(xr0 + 4 * fp) : float4{0.f, 0.f, 0.f, 0.f};
                float4 b4 = ok1 ? *(const float4*)(xr1 + 4 * fp) : float4{0.f, 0.f, 0.f, 0.f};
                unsigned u;
                u = (unsigned)f2bf(a4.x) | ((unsigned)f2bf(b4.x) << 16);
                ldsA32[(4 * fp + 0) * 18 + cp] = u;
                atomicAdd(&rnacc[4 * fp + 0], a4.x * a4.x + b4.x * b4.x);
                u = (unsigned)f2bf(a4.y) | ((unsigned)f2bf(b4.y) << 16);
                ldsA32[(4 * fp + 1) * 18 + cp] = u;
                atomicAdd(&rnacc[4 * fp + 1], a4.y * a4.y + b4.y * b4.y);
                u = (unsigned)f2bf(a4.z) | ((unsigned)f2bf(b4.z) << 16);
                ldsA32[(4 * fp + 2) * 18 + cp] = u;
                atomicAdd(&rnacc[4 * fp + 2], a4.z * a4.z + b4.z * b4.z);
                u = (unsigned)f2bf(a4.w) | ((unsigned)f2bf(b4.w) << 16);
                ldsA32[(4 * fp + 3) * 18 + cp] = u;
                atomicAdd(&rnacc[4 * fp + 3], a4.w * a4.w + b4.w * b4.w);
            }
        }
        __syncthreads();
        // ---- fragments + MFMA
        s8v bf[5];
#pragma unroll
        for (int ni = 0; ni < 5; ++ni)
            bf[ni] = *(const s8v*)(&ldsB[(ni * 16 + l15) * 40 + kg * 8]);
#pragma unroll
        for (int mi = 0; mi < 5; ++mi) {
            const short* ap = &ldsA[(wv * 80 + mi * 16 + l15) * 36 + kg * 8];
            s4v alo = *(const s4v*)ap;
            s4v ahi = *(const s4v*)(ap + 4);
            s8v av = __builtin_shufflevector(alo, ahi, 0, 1, 2, 3, 4, 5, 6, 7);
#pragma unroll
            for (int ni = 0; ni < 5; ++ni)
                acc[mi][ni] = __builtin_amdgcn_mfma_f32_16x16x32_bf16(av, bf[ni], acc[mi][ni], 0, 0, 0);
        }
    }
    __syncthreads();

    // rnorm finalize
    for (int f = tid; f < 400; f += 320) rnorm[f] = rsqrtf(rnacc[f] + EPS_);
    __syncthreads();

    // scale acc by frame rnorm
#pragma unroll
    for (int mi = 0; mi < 5; ++mi) {
        int f0 = wv * 80 + mi * 16 + kg * 4;
        float r0 = rnorm[f0], r1 = rnorm[f0 + 1], r2 = rnorm[f0 + 2], r3 = rnorm[f0 + 3];
#pragma unroll
        for (int ni = 0; ni < 5; ++ni) {
            acc[mi][ni][0] *= r0; acc[mi][ni][1] *= r1;
            acc[mi][ni][2] *= r2; acc[mi][ni][3] *= r3;
        }
    }

    // two pooling passes: pos then neg (shared pool buffer)
    unsigned stash[4];
    const int pp = tid % 80, wg = tid / 80;
    for (int pass = 0; pass < 2; ++pass) {
        float sgn = pass ? -1.f : 1.f;
#pragma unroll
        for (int mi = 0; mi < 5; ++mi) {
            int f0 = wv * 80 + mi * 16 + kg * 4;
            int w0 = f0 / 25, w3 = (f0 + 3) / 25;
            int wsplit = w3 * 25;
#pragma unroll
            for (int ni = 0; ni < 5; ++ni) {
                int pc = ni * 16 + l15;
                float m0 = -1e30f, m1 = -1e30f;
#pragma unroll
                for (int jj = 0; jj < 4; ++jj) {
                    float v = sgn * acc[mi][ni][jj];
                    if (f0 + jj < wsplit) m0 = fmaxf(m0, v);
                    else m1 = fmaxf(m1, v);
                }
                atomicMax(&pool[w3 * 80 + pc], okey(m1));
                if (w0 != w3) atomicMax(&pool[w0 * 80 + pc], okey(m0));
            }
        }
        __syncthreads();
        if (pass == 0) {
#pragma unroll
            for (int i2 = 0; i2 < 4; ++i2) stash[i2] = pool[(wg * 4 + i2) * 80 + pp];
            __syncthreads();
            for (int i2 = tid; i2 < 1280; i2 += 320) pool[i2] = 0u;
            __syncthreads();
        } else {
            float part = 0.f;
#pragma unroll
            for (int i2 = 0; i2 < 4; ++i2)
                part += dekey(stash[i2]) + dekey(pool[(wg * 4 + i2) * 80 + pp]);
            atomicAdd(&psum[pp], part);
        }
    }
    __syncthreads();
    if (tid < 80) {
        float rsap = 1.0f / (float)(length[b] / STRIDE_);
        atomicAdd(&pes[(size_t)b * P_ + pb * 80 + tid], psum[tid] * 0.5f * rsap);
    }
}

// ---------------- sparse graphs assembly + scalar outputs -------------------
__global__ __launch_bounds__(256) void graphs_kernel(const float* __restrict__ ws,
                                                     float* __restrict__ out) {
    int idx = blockIdx.x * 256 + threadIdx.x;
    if (idx == 0) {
        out[(size_t)B_ * N_ * N_] = ws[OFF_NORM];
        out[(size_t)B_ * N_ * N_ + 1] = ws[OFF_ORTH];
    }
    if (idx >= B_ * P_) return;
    int b = idx / P_;
    int p = idx - b * P_;

    float e = ws[OFF_PES + b * P_ + p];
    const float* keyval = ws + OFF_KEYVAL;
    const int* keyidx = (const int*)(ws + OFF_KEYIDX);
    float va[3] = { keyval[p * 4 + 0], keyval[p * 4 + 1], keyval[p * 4 + 2] };
    int ia[3] = { keyidx[p * 4 + 0], keyidx[p * 4 + 1], keyidx[p * 4 + 2] };

    float* g = out + (size_t)b * N_ * N_;
#pragma unroll
    for (int a = 0; a < 3; a++) {
#pragma unroll
        for (int c = 0; c < 3; c++) {
            float scale = (ia[a] == ia[c]) ? 1.0f : 6.0f;
            atomicAdd(&g[ia[a] * N_ + ia[c]], va[a] * va[c] * e * scale);
        }
    }
}

extern "C" void kernel_launch(void* const* d_in, const int* in_sizes, int n_in,
                              void* d_out, int out_size, void* d_ws, size_t ws_size,
                              hipStream_t stream) {
    const float* x = (const float*)d_in[0];
    const float* patterns = (const float*)d_in[1];
    const int* length = (const int*)d_in[2];
    float* out = (float*)d_out;
    float* ws = (float*)d_ws;

    hipMemsetAsync(ws + OFF_PES, 0, (size_t)(B_ * P_ + 2) * sizeof(float), stream);
    hipMemsetAsync(d_out, 0, (size_t)B_ * N_ * N_ * sizeof(float), stream);

    pat_kernel<<<P_, 64, 0, stream>>>(patterns, ws);
    orth_kernel<<<P_, 256, 0, stream>>>(ws);
    mfma_kernel<<<dim3(5, 3, B_), 320, 0, stream>>>(x, length, ws, ws + OFF_PES);
    graphs_kernel<<<(B_ * P_ + 255) / 256, 256, 0, stream>>>(ws, out);
}

// Round 3
// 151.871 us; speedup vs baseline: 2.3400x; 2.3400x over previous
//
#include <hip/hip_runtime.h>
#include <math.h>

#define B_ 64
#define N_ 200
#define P_ 400
#define T_ 1200
#define STRIDE_ 25
#define EPS_ 1e-9f
#define KPAD 224

// ws layout (float offsets)
#define OFF_NPATT  0            // [N_][P_] f32 transposed normalized patterns (80000)
#define OFF_NPB16  80000        // [P_][KPAD] bf16 normalized patterns (89600 u16)
#define OFF_KEYVAL 124800       // [P_][4]
#define OFF_KEYIDX 126400       // [P_][4] int
#define OFF_PES    128000       // [B_][P_]
#define OFF_NORM   153600
#define OFF_ORTH   153601
#define OFF_XN     153604       // [B_][T_][KPAD] bf16 normalized frames (8,601,600 f32 slots)
#define WS_FAST_FLOATS (153604 + 8601600)

typedef float f4v __attribute__((ext_vector_type(4)));
typedef short s8v __attribute__((ext_vector_type(8)));
typedef short s4v __attribute__((ext_vector_type(4)));

__device__ inline unsigned short f2bf(float f) {
    union { float f; unsigned u; } v; v.f = f;
    unsigned r = v.u + 0x7FFFu + ((v.u >> 16) & 1u);
    return (unsigned short)(r >> 16);
}
__device__ inline unsigned okey(float f) {
    unsigned u = __float_as_uint(f);
    return (u & 0x80000000u) ? ~u : (u | 0x80000000u);
}
__device__ inline float dekey(unsigned k) {
    unsigned u = (k & 0x80000000u) ? (k & 0x7fffffffu) : ~k;
    return __uint_as_float(u);
}

// ---------------- pattern preprocessing: normalize rows, top-3, norm scalar ----
__global__ __launch_bounds__(64) void pat_kernel(const float* __restrict__ patterns,
                                                 float* __restrict__ ws) {
    int p = blockIdx.x;
    int lane = threadIdx.x;

    float v0 = patterns[p * N_ + lane];
    float v1 = patterns[p * N_ + lane + 64];
    float v2 = patterns[p * N_ + lane + 128];
    float v3 = (lane < 8) ? patterns[p * N_ + lane + 192] : 0.0f;

    float ss = v0 * v0 + v1 * v1 + v2 * v2 + v3 * v3;
    for (int off = 32; off; off >>= 1) ss += __shfl_down(ss, off);
    ss = __shfl(ss, 0);

    float rn = 1.0f / sqrtf(ss + EPS_);
    float s0 = v0 * rn, s1 = v1 * rn, s2 = v2 * rn, s3 = v3 * rn;

    float* npatT = ws + OFF_NPATT;
    npatT[(lane) * P_ + p] = s0;
    npatT[(lane + 64) * P_ + p] = s1;
    npatT[(lane + 128) * P_ + p] = s2;
    if (lane < 8) npatT[(lane + 192) * P_ + p] = s3;

    unsigned short* npb = (unsigned short*)(ws + OFF_NPB16);
    npb[p * KPAD + lane] = f2bf(s0);
    npb[p * KPAD + lane + 64] = f2bf(s1);
    npb[p * KPAD + lane + 128] = f2bf(s2);
    if (lane < 8) npb[p * KPAD + lane + 192] = f2bf(s3);
    if (lane < 24) npb[p * KPAD + 200 + lane] = 0;

    float a0 = fabsf(s0), a1 = fabsf(s1), a2 = fabsf(s2);
    float a3 = fabsf(s3);

    int ch0 = -1, ch1 = -1, ch2 = -1;
    float cs0 = 0.f, cs1 = 0.f, cs2 = 0.f;

    for (int r = 0; r < 3; r++) {
        float bv = -1.0f;
        int bi = 1 << 30;
        {
            int n = lane;
            bool sk = (n == ch0) || (n == ch1) || (n == ch2);
            if (!sk && a0 > bv) { bv = a0; bi = n; }
        }
        {
            int n = lane + 64;
            bool sk = (n == ch0) || (n == ch1) || (n == ch2);
            if (!sk && (a1 > bv || (a1 == bv && n < bi))) { bv = a1; bi = n; }
        }
        {
            int n = lane + 128;
            bool sk = (n == ch0) || (n == ch1) || (n == ch2);
            if (!sk && (a2 > bv || (a2 == bv && n < bi))) { bv = a2; bi = n; }
        }
        if (lane < 8) {
            int n = lane + 192;
            bool sk = (n == ch0) || (n == ch1) || (n == ch2);
            if (!sk && (a3 > bv || (a3 == bv && n < bi))) { bv = a3; bi = n; }
        }
        for (int off = 32; off; off >>= 1) {
            float ov = __shfl_down(bv, off);
            int oi = __shfl_down(bi, off);
            if (ov > bv || (ov == bv && oi < bi)) { bv = ov; bi = oi; }
        }
        bi = __shfl(bi, 0);
        int slot = bi >> 6, src = bi & 63;
        float mine = (slot == 0) ? s0 : (slot == 1) ? s1 : (slot == 2) ? s2 : s3;
        float sval = __shfl(mine, src);
        if (r == 0) { ch0 = bi; cs0 = sval; }
        else if (r == 1) { ch1 = bi; cs1 = sval; }
        else { ch2 = bi; cs2 = sval; }
    }

    if (lane == 0) {
        float* keyval = ws + OFF_KEYVAL;
        int* keyidx = (int*)(ws + OFF_KEYIDX);
        keyval[p * 4 + 0] = cs0; keyval[p * 4 + 1] = cs1; keyval[p * 4 + 2] = cs2;
        keyidx[p * 4 + 0] = ch0; keyidx[p * 4 + 1] = ch1; keyidx[p * 4 + 2] = ch2;
        float lenp = sqrtf(ss) * rn;
        float lentopp = sqrtf(cs0 * cs0 + cs1 * cs1 + cs2 * cs2);
        float d = 1.0f - lentopp / lenp;
        atomicAdd(ws + OFF_NORM, d * d * (1.0f / (float)P_));
    }
}

// ---------------- orth regularizer -----------------------------------------
__global__ __launch_bounds__(256) void orth_kernel(float* __restrict__ ws) {
    __shared__ float rowi[N_];
    __shared__ float red[256];
    const float* npatT = ws + OFF_NPATT;
    int i = blockIdx.x;
    for (int k = threadIdx.x; k < N_; k += 256) rowi[k] = npatT[k * P_ + i];
    __syncthreads();

    float partial = 0.0f;
    for (int j = threadIdx.x; j < P_; j += 256) {
        if (j == i) continue;
        float s = 0.0f;
        for (int k = 0; k < N_; k++) s += rowi[k] * npatT[k * P_ + j];
        float t = (fabsf(s) - 0.3f) * (1.0f / 0.70001f);
        if (t > 0.0f) partial += t * t;
    }
    red[threadIdx.x] = partial;
    __syncthreads();
    for (int sft = 128; sft; sft >>= 1) {
        if (threadIdx.x < sft) red[threadIdx.x] += red[threadIdx.x + sft];
        __syncthreads();
    }
    if (threadIdx.x == 0)
        atomicAdd(ws + OFF_ORTH, red[0] * (1.0f / ((float)P_ * (float)P_)));
}

// ---------------- transpose + frame-normalize -> bf16 xn --------------------
// block: 256 thr = (r 0..3) x (t 0..63); tile = one b, 64 frames, all 200 chans.
__global__ __launch_bounds__(256) void tnorm_kernel(const float* __restrict__ x,
                                                    float* __restrict__ ws) {
    __shared__ unsigned short xt16[64 * 210];    // bf16 staging, stride 210 (105 dw, odd)
    __shared__ float psums[256];
    __shared__ float rns[64];

    const int tid = threadIdx.x;
    const int t = tid & 63, r = tid >> 6;
    const int b = blockIdx.y;
    const int t0 = blockIdx.x * 64;
    const bool valid = (t0 + t) < T_;

    float ss = 0.0f;
    if (valid) {
        const float* xp = x + (size_t)b * N_ * T_ + t0 + t;
#pragma unroll 5
        for (int i = 0; i < 50; ++i) {
            int n = r * 50 + i;
            float v = xp[(size_t)n * T_];
            ss += v * v;
            xt16[t * 210 + n] = f2bf(v);
        }
    }
    psums[tid] = ss;
    __syncthreads();
    if (tid < 64) {
        float s = psums[tid] + psums[tid + 64] + psums[tid + 128] + psums[tid + 192];
        rns[tid] = rsqrtf(s + EPS_);
    }
    __syncthreads();

    unsigned short* xn = (unsigned short*)(ws + OFF_XN);
#pragma unroll
    for (int j = 0; j < 7; ++j) {
        int idx = tid + 256 * j;            // 1792 = 64 t x 28 segs
        int tt = idx / 28, s = idx % 28;
        if (t0 + tt >= T_) continue;
        s8v ov = (s8v){0, 0, 0, 0, 0, 0, 0, 0};
        if (s < 25) {
            float rn = rns[tt];
            const unsigned* src = (const unsigned*)&xt16[tt * 210 + s * 8];
            unsigned o[4];
#pragma unroll
            for (int i = 0; i < 4; ++i) {
                unsigned u = src[i];
                float lo = __uint_as_float(u << 16) * rn;
                float hi = __uint_as_float(u & 0xffff0000u) * rn;
                o[i] = (unsigned)f2bf(lo) | ((unsigned)f2bf(hi) << 16);
            }
            ov = (s8v){(short)(o[0] & 0xffff), (short)(o[0] >> 16),
                       (short)(o[1] & 0xffff), (short)(o[1] >> 16),
                       (short)(o[2] & 0xffff), (short)(o[2] >> 16),
                       (short)(o[3] & 0xffff), (short)(o[3] >> 16)};
        }
        *(s8v*)(xn + ((size_t)b * T_ + t0 + tt) * KPAD + s * 8) = ov;
    }
}

// ---------------- MFMA GEMM + fused window pooling -> PES -------------------
// grid (5 pblocks, 3 mblocks, 64 b); block 320 thr = 5 waves.
// Tile: M=400 frames (16 windows exactly), N=80 patterns, K=224 (7 chunks of 32).
__global__ __launch_bounds__(320, 3) void gemm_kernel(const float* __restrict__ ws,
                                                      const int* __restrict__ length,
                                                      float* __restrict__ pes) {
    __shared__ short ldsA[400 * 36];       // [frame][k] bf16, stride 36 (18 dw, cf-free)
    __shared__ short ldsB[80 * 40];        // [pat][k] bf16, stride 40
    __shared__ unsigned pool[16 * 80];     // ordered-uint max pool
    __shared__ float psum[80];

    const int tid = threadIdx.x;
    const int pb = blockIdx.x;
    const int mb = blockIdx.y;
    const int b  = blockIdx.z;

    for (int i = tid; i < 1280; i += 320) pool[i] = 0u;
    if (tid < 80) psum[tid] = 0.f;

    f4v acc[5][5];
#pragma unroll
    for (int mi = 0; mi < 5; ++mi)
#pragma unroll
        for (int ni = 0; ni < 5; ++ni) acc[mi][ni] = (f4v){0.f, 0.f, 0.f, 0.f};

    const int wv = tid >> 6;
    const int lane = tid & 63;
    const int l15 = lane & 15, kg = lane >> 4;

    const unsigned short* npb = (const unsigned short*)(ws + OFF_NPB16) + (size_t)(pb * 80) * KPAD;
    const unsigned short* xb = (const unsigned short*)(ws + OFF_XN) +
                               ((size_t)b * T_ + (size_t)mb * 400) * KPAD;

    for (int c = 0; c < 7; ++c) {
        __syncthreads();
        // stage B chunk: 80 pats x 32 k
        {
            int p = tid >> 2, kh = tid & 3;
            s8v bv = *(const s8v*)(npb + (size_t)p * KPAD + c * 32 + kh * 8);
            *(s8v*)(&ldsB[p * 40 + kh * 8]) = bv;
        }
        // stage A chunk: 400 frames x 32 k (pure bf16 copy)
#pragma unroll
        for (int j = 0; j < 5; ++j) {
            int idx = tid + 320 * j;
            int row = idx >> 2, seg = idx & 3;
            s8v av = *(const s8v*)(xb + (size_t)row * KPAD + c * 32 + seg * 8);
            *(s4v*)(&ldsA[row * 36 + seg * 8]) =
                __builtin_shufflevector(av, av, 0, 1, 2, 3);
            *(s4v*)(&ldsA[row * 36 + seg * 8 + 4]) =
                __builtin_shufflevector(av, av, 4, 5, 6, 7);
        }
        __syncthreads();
        // fragments + MFMA
        s8v bf[5];
#pragma unroll
        for (int ni = 0; ni < 5; ++ni)
            bf[ni] = *(const s8v*)(&ldsB[(ni * 16 + l15) * 40 + kg * 8]);
#pragma unroll
        for (int mi = 0; mi < 5; ++mi) {
            const short* ap = &ldsA[(wv * 80 + mi * 16 + l15) * 36 + kg * 8];
            s4v alo = *(const s4v*)ap;
            s4v ahi = *(const s4v*)(ap + 4);
            s8v av = __builtin_shufflevector(alo, ahi, 0, 1, 2, 3, 4, 5, 6, 7);
#pragma unroll
            for (int ni = 0; ni < 5; ++ni)
                acc[mi][ni] = __builtin_amdgcn_mfma_f32_16x16x32_bf16(av, bf[ni], acc[mi][ni], 0, 0, 0);
        }
    }
    __syncthreads();

    // two pooling passes: pos then neg (shared pool buffer)
    unsigned stash[4];
    const int pp = tid % 80, wg = tid / 80;
    for (int pass = 0; pass < 2; ++pass) {
        float sgn = pass ? -1.f : 1.f;
#pragma unroll
        for (int mi = 0; mi < 5; ++mi) {
            int f0 = wv * 80 + mi * 16 + kg * 4;
            int w0 = f0 / 25, w3 = (f0 + 3) / 25;
            int wsplit = w3 * 25;
#pragma unroll
            for (int ni = 0; ni < 5; ++ni) {
                int pc = ni * 16 + l15;
                float m0 = -1e30f, m1 = -1e30f;
#pragma unroll
                for (int jj = 0; jj < 4; ++jj) {
                    float v = sgn * acc[mi][ni][jj];
                    if (f0 + jj < wsplit) m0 = fmaxf(m0, v);
                    else m1 = fmaxf(m1, v);
                }
                atomicMax(&pool[w3 * 80 + pc], okey(m1));
                if (w0 != w3) atomicMax(&pool[w0 * 80 + pc], okey(m0));
            }
        }
        __syncthreads();
        if (pass == 0) {
#pragma unroll
            for (int i2 = 0; i2 < 4; ++i2) stash[i2] = pool[(wg * 4 + i2) * 80 + pp];
            __syncthreads();
            for (int i2 = tid; i2 < 1280; i2 += 320) pool[i2] = 0u;
            __syncthreads();
        } else {
            float part = 0.f;
#pragma unroll
            for (int i2 = 0; i2 < 4; ++i2)
                part += dekey(stash[i2]) + dekey(pool[(wg * 4 + i2) * 80 + pp]);
            atomicAdd(&psum[pp], part);
        }
    }
    __syncthreads();
    if (tid < 80) {
        float rsap = 1.0f / (float)(length[b] / STRIDE_);
        atomicAdd(&pes[(size_t)b * P_ + pb * 80 + tid], psum[tid] * 0.5f * rsap);
    }
}

// ---------------- fallback fp32 fused GEMM+pool (R1, used if ws too small) ----
__global__ __launch_bounds__(256) void main_kernel(const float* __restrict__ x,
                                                   const int* __restrict__ length,
                                                   const float* __restrict__ ws,
                                                   float* __restrict__ pes) {
    __shared__ float xs[N_][STRIDE_ + 1];
    __shared__ float rnorm[STRIDE_];
    __shared__ float poolp[P_][5];
    __shared__ float pooln[P_][5];

    int w = blockIdx.x;
    int b = blockIdx.y;
    const float* xb = x + (size_t)b * N_ * T_ + (size_t)w * STRIDE_;

    for (int i = threadIdx.x; i < N_ * STRIDE_; i += 256) {
        int n = i / STRIDE_;
        int t = i - n * STRIDE_;
        xs[n][t] = xb[n * T_ + t];
    }
    __syncthreads();

    if (threadIdx.x < STRIDE_) {
        float ssf = 0.0f;
        for (int n = 0; n < N_; n++) { float vv = xs[n][threadIdx.x]; ssf += vv * vv; }
        rnorm[threadIdx.x] = 1.0f / sqrtf(ssf + EPS_);
    }
    __syncthreads();

    int pt = threadIdx.x % 50;
    int tt = threadIdx.x / 50;

    if (tt < 5) {
        float acc[8][5];
#pragma unroll
        for (int i = 0; i < 8; i++)
#pragma unroll
            for (int j = 0; j < 5; j++) acc[i][j] = 0.0f;

        const float4* np4 = (const float4*)(ws + OFF_NPATT);
        int pbq = pt * 2;
        for (int n = 0; n < N_; n++) {
            float4 q0 = np4[n * (P_ / 4) + pbq];
            float4 q1 = np4[n * (P_ / 4) + pbq + 1];
            float qa[8] = { q0.x, q0.y, q0.z, q0.w, q1.x, q1.y, q1.z, q1.w };
            float xv0 = xs[n][tt * 5 + 0];
            float xv1 = xs[n][tt * 5 + 1];
            float xv2 = xs[n][tt * 5 + 2];
            float xv3 = xs[n][tt * 5 + 3];
            float xv4 = xs[n][tt * 5 + 4];
#pragma unroll
            for (int i = 0; i < 8; i++) {
                acc[i][0] += qa[i] * xv0;
                acc[i][1] += qa[i] * xv1;
                acc[i][2] += qa[i] * xv2;
                acc[i][3] += qa[i] * xv3;
                acc[i][4] += qa[i] * xv4;
            }
        }
#pragma unroll
        for (int i = 0; i < 8; i++) {
            float pm = -1e30f, nm = -1e30f;
#pragma unroll
            for (int j = 0; j < 5; j++) {
                float s = acc[i][j] * rnorm[tt * 5 + j];
                pm = fmaxf(pm, s);
                nm = fmaxf(nm, -s);
            }
            poolp[pt * 8 + i][tt] = pm;
            pooln[pt * 8 + i][tt] = nm;
        }
    }
    __syncthreads();

    float rsap = 1.0f / (float)(length[b] / STRIDE_);
    for (int p = threadIdx.x; p < P_; p += 256) {
        float pm = poolp[p][0], nm = pooln[p][0];
#pragma unroll
        for (int q = 1; q < 5; q++) {
            pm = fmaxf(pm, poolp[p][q]);
            nm = fmaxf(nm, pooln[p][q]);
        }
        atomicAdd(&pes[b * P_ + p], (pm + nm) * 0.5f * rsap);
    }
}

// ---------------- sparse graphs assembly + scalar outputs -------------------
__global__ __launch_bounds__(256) void graphs_kernel(const float* __restrict__ ws,
                                                     float* __restrict__ out) {
    int idx = blockIdx.x * 256 + threadIdx.x;
    if (idx == 0) {
        out[(size_t)B_ * N_ * N_] = ws[OFF_NORM];
        out[(size_t)B_ * N_ * N_ + 1] = ws[OFF_ORTH];
    }
    if (idx >= B_ * P_) return;
    int b = idx / P_;
    int p = idx - b * P_;

    float e = ws[OFF_PES + b * P_ + p];
    const float* keyval = ws + OFF_KEYVAL;
    const int* keyidx = (const int*)(ws + OFF_KEYIDX);
    float va[3] = { keyval[p * 4 + 0], keyval[p * 4 + 1], keyval[p * 4 + 2] };
    int ia[3] = { keyidx[p * 4 + 0], keyidx[p * 4 + 1], keyidx[p * 4 + 2] };

    float* g = out + (size_t)b * N_ * N_;
#pragma unroll
    for (int a = 0; a < 3; a++) {
#pragma unroll
        for (int c = 0; c < 3; c++) {
            float scale = (ia[a] == ia[c]) ? 1.0f : 6.0f;
            atomicAdd(&g[ia[a] * N_ + ia[c]], va[a] * va[c] * e * scale);
        }
    }
}

extern "C" void kernel_launch(void* const* d_in, const int* in_sizes, int n_in,
                              void* d_out, int out_size, void* d_ws, size_t ws_size,
                              hipStream_t stream) {
    const float* x = (const float*)d_in[0];
    const float* patterns = (const float*)d_in[1];
    const int* length = (const int*)d_in[2];
    float* out = (float*)d_out;
    float* ws = (float*)d_ws;

    hipMemsetAsync(ws + OFF_PES, 0, (size_t)(B_ * P_ + 2) * sizeof(float), stream);
    hipMemsetAsync(d_out, 0, (size_t)B_ * N_ * N_ * sizeof(float), stream);

    pat_kernel<<<P_, 64, 0, stream>>>(patterns, ws);
    orth_kernel<<<P_, 256, 0, stream>>>(ws);

    if (ws_size >= (size_t)WS_FAST_FLOATS * sizeof(float)) {
        tnorm_kernel<<<dim3((T_ + 63) / 64, B_), 256, 0, stream>>>(x, ws);
        gemm_kernel<<<dim3(5, 3, B_), 320, 0, stream>>>(ws, length, ws + OFF_PES);
    } else {
        main_kernel<<<dim3(T_ / STRIDE_, B_), 256, 0, stream>>>(x, length, ws, ws + OFF_PES);
    }
    graphs_kernel<<<(B_ * P_ + 255) / 256, 256, 0, stream>>>(ws, out);
}

// Round 4
// 135.946 us; speedup vs baseline: 2.6141x; 1.1171x over previous
//
#include <hip/hip_runtime.h>
#include <math.h>

#define B_ 64
#define N_ 200
#define P_ 400
#define T_ 1200
#define STRIDE_ 25
#define EPS_ 1e-9f
#define KPAD 224
#define BSTRIDE 232   // LDS B row stride in shorts: 464B = 116 dw -> 2-way max (free)

// ws layout (float offsets)
#define OFF_NPATT  0            // [N_][P_] f32 transposed normalized patterns (80000)
#define OFF_NPB16  80000        // [P_][KPAD] bf16 normalized patterns (89600 u16)
#define OFF_KEYVAL 124800       // [P_][4]
#define OFF_KEYIDX 126400       // [P_][4] int
#define OFF_PES    128000       // [B_][P_]
#define OFF_NORM   153600
#define OFF_ORTH   153601
#define OFF_XN     153604       // [B_][T_][KPAD] bf16 normalized frames
#define WS_FAST_FLOATS (153604 + 8601600)

typedef float f4v __attribute__((ext_vector_type(4)));
typedef short s8v __attribute__((ext_vector_type(8)));
typedef short s4v __attribute__((ext_vector_type(4)));

__device__ inline unsigned short f2bf(float f) {
    union { float f; unsigned u; } v; v.f = f;
    unsigned r = v.u + 0x7FFFu + ((v.u >> 16) & 1u);
    return (unsigned short)(r >> 16);
}
__device__ inline unsigned okey(float f) {
    unsigned u = __float_as_uint(f);
    return (u & 0x80000000u) ? ~u : (u | 0x80000000u);
}
__device__ inline float dekey(unsigned k) {
    unsigned u = (k & 0x80000000u) ? (k & 0x7fffffffu) : ~k;
    return __uint_as_float(u);
}

// ---------------- pattern preprocessing: normalize rows, top-3, norm scalar ----
__global__ __launch_bounds__(64) void pat_kernel(const float* __restrict__ patterns,
                                                 float* __restrict__ ws) {
    int p = blockIdx.x;
    int lane = threadIdx.x;

    float v0 = patterns[p * N_ + lane];
    float v1 = patterns[p * N_ + lane + 64];
    float v2 = patterns[p * N_ + lane + 128];
    float v3 = (lane < 8) ? patterns[p * N_ + lane + 192] : 0.0f;

    float ss = v0 * v0 + v1 * v1 + v2 * v2 + v3 * v3;
    for (int off = 32; off; off >>= 1) ss += __shfl_down(ss, off);
    ss = __shfl(ss, 0);

    float rn = 1.0f / sqrtf(ss + EPS_);
    float s0 = v0 * rn, s1 = v1 * rn, s2 = v2 * rn, s3 = v3 * rn;

    float* npatT = ws + OFF_NPATT;
    npatT[(lane) * P_ + p] = s0;
    npatT[(lane + 64) * P_ + p] = s1;
    npatT[(lane + 128) * P_ + p] = s2;
    if (lane < 8) npatT[(lane + 192) * P_ + p] = s3;

    unsigned short* npb = (unsigned short*)(ws + OFF_NPB16);
    npb[p * KPAD + lane] = f2bf(s0);
    npb[p * KPAD + lane + 64] = f2bf(s1);
    npb[p * KPAD + lane + 128] = f2bf(s2);
    if (lane < 8) npb[p * KPAD + lane + 192] = f2bf(s3);
    if (lane < 24) npb[p * KPAD + 200 + lane] = 0;

    float a0 = fabsf(s0), a1 = fabsf(s1), a2 = fabsf(s2);
    float a3 = fabsf(s3);

    int ch0 = -1, ch1 = -1, ch2 = -1;
    float cs0 = 0.f, cs1 = 0.f, cs2 = 0.f;

    for (int r = 0; r < 3; r++) {
        float bv = -1.0f;
        int bi = 1 << 30;
        {
            int n = lane;
            bool sk = (n == ch0) || (n == ch1) || (n == ch2);
            if (!sk && a0 > bv) { bv = a0; bi = n; }
        }
        {
            int n = lane + 64;
            bool sk = (n == ch0) || (n == ch1) || (n == ch2);
            if (!sk && (a1 > bv || (a1 == bv && n < bi))) { bv = a1; bi = n; }
        }
        {
            int n = lane + 128;
            bool sk = (n == ch0) || (n == ch1) || (n == ch2);
            if (!sk && (a2 > bv || (a2 == bv && n < bi))) { bv = a2; bi = n; }
        }
        if (lane < 8) {
            int n = lane + 192;
            bool sk = (n == ch0) || (n == ch1) || (n == ch2);
            if (!sk && (a3 > bv || (a3 == bv && n < bi))) { bv = a3; bi = n; }
        }
        for (int off = 32; off; off >>= 1) {
            float ov = __shfl_down(bv, off);
            int oi = __shfl_down(bi, off);
            if (ov > bv || (ov == bv && oi < bi)) { bv = ov; bi = oi; }
        }
        bi = __shfl(bi, 0);
        int slot = bi >> 6, src = bi & 63;
        float mine = (slot == 0) ? s0 : (slot == 1) ? s1 : (slot == 2) ? s2 : s3;
        float sval = __shfl(mine, src);
        if (r == 0) { ch0 = bi; cs0 = sval; }
        else if (r == 1) { ch1 = bi; cs1 = sval; }
        else { ch2 = bi; cs2 = sval; }
    }

    if (lane == 0) {
        float* keyval = ws + OFF_KEYVAL;
        int* keyidx = (int*)(ws + OFF_KEYIDX);
        keyval[p * 4 + 0] = cs0; keyval[p * 4 + 1] = cs1; keyval[p * 4 + 2] = cs2;
        keyidx[p * 4 + 0] = ch0; keyidx[p * 4 + 1] = ch1; keyidx[p * 4 + 2] = ch2;
        float lenp = sqrtf(ss) * rn;
        float lentopp = sqrtf(cs0 * cs0 + cs1 * cs1 + cs2 * cs2);
        float d = 1.0f - lentopp / lenp;
        atomicAdd(ws + OFF_NORM, d * d * (1.0f / (float)P_));
    }
}

// ---------------- orth regularizer -----------------------------------------
__global__ __launch_bounds__(256) void orth_kernel(float* __restrict__ ws) {
    __shared__ float rowi[N_];
    __shared__ float red[256];
    const float* npatT = ws + OFF_NPATT;
    int i = blockIdx.x;
    for (int k = threadIdx.x; k < N_; k += 256) rowi[k] = npatT[k * P_ + i];
    __syncthreads();

    float partial = 0.0f;
    for (int j = threadIdx.x; j < P_; j += 256) {
        if (j == i) continue;
        float s = 0.0f;
        for (int k = 0; k < N_; k++) s += rowi[k] * npatT[k * P_ + j];
        float t = (fabsf(s) - 0.3f) * (1.0f / 0.70001f);
        if (t > 0.0f) partial += t * t;
    }
    red[threadIdx.x] = partial;
    __syncthreads();
    for (int sft = 128; sft; sft >>= 1) {
        if (threadIdx.x < sft) red[threadIdx.x] += red[threadIdx.x + sft];
        __syncthreads();
    }
    if (threadIdx.x == 0)
        atomicAdd(ws + OFF_ORTH, red[0] * (1.0f / ((float)P_ * (float)P_)));
}

// ---------------- transpose + frame-normalize -> bf16 xn --------------------
__global__ __launch_bounds__(256) void tnorm_kernel(const float* __restrict__ x,
                                                    float* __restrict__ ws) {
    __shared__ unsigned short xt16[64 * 210];
    __shared__ float psums[256];
    __shared__ float rns[64];

    const int tid = threadIdx.x;
    const int t = tid & 63, r = tid >> 6;
    const int b = blockIdx.y;
    const int t0 = blockIdx.x * 64;
    const bool valid = (t0 + t) < T_;

    float ss = 0.0f;
    if (valid) {
        const float* xp = x + (size_t)b * N_ * T_ + t0 + t;
#pragma unroll 5
        for (int i = 0; i < 50; ++i) {
            int n = r * 50 + i;
            float v = xp[(size_t)n * T_];
            ss += v * v;
            xt16[t * 210 + n] = f2bf(v);
        }
    }
    psums[tid] = ss;
    __syncthreads();
    if (tid < 64) {
        float s = psums[tid] + psums[tid + 64] + psums[tid + 128] + psums[tid + 192];
        rns[tid] = rsqrtf(s + EPS_);
    }
    __syncthreads();

    unsigned short* xn = (unsigned short*)(ws + OFF_XN);
#pragma unroll
    for (int j = 0; j < 7; ++j) {
        int idx = tid + 256 * j;
        int tt = idx / 28, s = idx % 28;
        if (t0 + tt >= T_) continue;
        s8v ov = (s8v){0, 0, 0, 0, 0, 0, 0, 0};
        if (s < 25) {
            float rn = rns[tt];
            const unsigned* src = (const unsigned*)&xt16[tt * 210 + s * 8];
            unsigned o[4];
#pragma unroll
            for (int i = 0; i < 4; ++i) {
                unsigned u = src[i];
                float lo = __uint_as_float(u << 16) * rn;
                float hi = __uint_as_float(u & 0xffff0000u) * rn;
                o[i] = (unsigned)f2bf(lo) | ((unsigned)f2bf(hi) << 16);
            }
            ov = (s8v){(short)(o[0] & 0xffff), (short)(o[0] >> 16),
                       (short)(o[1] & 0xffff), (short)(o[1] >> 16),
                       (short)(o[2] & 0xffff), (short)(o[2] >> 16),
                       (short)(o[3] & 0xffff), (short)(o[3] >> 16)};
        }
        *(s8v*)(xn + ((size_t)b * T_ + t0 + tt) * KPAD + s * 8) = ov;
    }
}

// ---------------- barrier-free MFMA GEMM + fused window pooling -> PES ------
// 960 blocks (5 pb x 3 mb x 64 b, XCD-swizzled), 320 thr = 5 waves.
// B (80x224 bf16) staged in LDS ONCE; A streamed global->VGPR with 1-chunk
// prefetch; zero __syncthreads in the K-loop.
__global__ __launch_bounds__(320, 2) void gemm_kernel(const float* __restrict__ ws,
                                                      const int* __restrict__ length,
                                                      float* __restrict__ pes) {
    __shared__ short ldsB[80 * BSTRIDE];   // 37.1 KB
    __shared__ unsigned pool[16 * 80];
    __shared__ float psum[80];

    const int tid = threadIdx.x;
    // bijective XCD swizzle: 960 blocks, 8 XCDs, 120 blocks each; consecutive
    // original ids (same A-tile, 5 pb) land on one XCD's L2.
    int id = blockIdx.x + 5 * (blockIdx.y + 3 * (int)blockIdx.z);
    int nid = (id & 7) * 120 + (id >> 3);
    const int pb = nid % 5;
    const int mb = (nid / 5) % 3;
    const int b  = nid / 15;

    const unsigned short* npb = (const unsigned short*)(ws + OFF_NPB16) + (size_t)(pb * 80) * KPAD;

    // stage ALL of B: 80 rows x 224 shorts = 2240 16B units, 7 per thread
#pragma unroll
    for (int j = 0; j < 7; ++j) {
        int idx = tid + 320 * j;
        int row = idx / 28, seg = idx % 28;
        *(s8v*)(&ldsB[row * BSTRIDE + seg * 8]) = *(const s8v*)(npb + (size_t)row * KPAD + seg * 8);
    }
    for (int i = tid; i < 1280; i += 320) pool[i] = 0u;
    if (tid < 80) psum[tid] = 0.f;
    __syncthreads();                       // the only barrier before epilogue

    const int wv = tid >> 6;
    const int lane = tid & 63;
    const int l15 = lane & 15, kg = lane >> 4;

    f4v acc[5][5];
#pragma unroll
    for (int mi = 0; mi < 5; ++mi)
#pragma unroll
        for (int ni = 0; ni < 5; ++ni) acc[mi][ni] = (f4v){0.f, 0.f, 0.f, 0.f};

    // A row pointers: wave wv owns frames [wv*80, wv*80+80)
    const unsigned short* xb = (const unsigned short*)(ws + OFF_XN) +
                               ((size_t)b * T_ + (size_t)mb * 400) * KPAD;
    const unsigned short* ar[5];
#pragma unroll
    for (int mi = 0; mi < 5; ++mi)
        ar[mi] = xb + (size_t)(wv * 80 + mi * 16 + l15) * KPAD + kg * 8;

    s8v a0[5], a1[5];
#pragma unroll
    for (int mi = 0; mi < 5; ++mi) a0[mi] = *(const s8v*)(ar[mi]);   // chunk 0

#pragma unroll
    for (int c = 0; c < 7; ++c) {
        // prefetch next A chunk into the other parity set
        if (c < 6) {
            if ((c & 1) == 0) {
#pragma unroll
                for (int mi = 0; mi < 5; ++mi) a1[mi] = *(const s8v*)(ar[mi] + (c + 1) * 32);
            } else {
#pragma unroll
                for (int mi = 0; mi < 5; ++mi) a0[mi] = *(const s8v*)(ar[mi] + (c + 1) * 32);
            }
        }
        // B fragments for this chunk (read-only LDS, no barrier needed)
        s8v bf[5];
#pragma unroll
        for (int ni = 0; ni < 5; ++ni)
            bf[ni] = *(const s8v*)(&ldsB[(ni * 16 + l15) * BSTRIDE + c * 32 + kg * 8]);

#pragma unroll
        for (int mi = 0; mi < 5; ++mi) {
            s8v av = ((c & 1) == 0) ? a0[mi] : a1[mi];
#pragma unroll
            for (int ni = 0; ni < 5; ++ni)
                acc[mi][ni] = __builtin_amdgcn_mfma_f32_16x16x32_bf16(av, bf[ni], acc[mi][ni], 0, 0, 0);
        }
    }
    __syncthreads();

    // two pooling passes: pos then neg (shared pool buffer) — verified epilogue
    unsigned stash[4];
    const int pp = tid % 80, wg = tid / 80;
    for (int pass = 0; pass < 2; ++pass) {
        float sgn = pass ? -1.f : 1.f;
#pragma unroll
        for (int mi = 0; mi < 5; ++mi) {
            int f0 = wv * 80 + mi * 16 + kg * 4;
            int w0 = f0 / 25, w3 = (f0 + 3) / 25;
            int wsplit = w3 * 25;
#pragma unroll
            for (int ni = 0; ni < 5; ++ni) {
                int pc = ni * 16 + l15;
                float m0 = -1e30f, m1 = -1e30f;
#pragma unroll
                for (int jj = 0; jj < 4; ++jj) {
                    float v = sgn * acc[mi][ni][jj];
                    if (f0 + jj < wsplit) m0 = fmaxf(m0, v);
                    else m1 = fmaxf(m1, v);
                }
                atomicMax(&pool[w3 * 80 + pc], okey(m1));
                if (w0 != w3) atomicMax(&pool[w0 * 80 + pc], okey(m0));
            }
        }
        __syncthreads();
        if (pass == 0) {
#pragma unroll
            for (int i2 = 0; i2 < 4; ++i2) stash[i2] = pool[(wg * 4 + i2) * 80 + pp];
            __syncthreads();
            for (int i2 = tid; i2 < 1280; i2 += 320) pool[i2] = 0u;
            __syncthreads();
        } else {
            float part = 0.f;
#pragma unroll
            for (int i2 = 0; i2 < 4; ++i2)
                part += dekey(stash[i2]) + dekey(pool[(wg * 4 + i2) * 80 + pp]);
            atomicAdd(&psum[pp], part);
        }
    }
    __syncthreads();
    if (tid < 80) {
        float rsap = 1.0f / (float)(length[b] / STRIDE_);
        atomicAdd(&pes[(size_t)b * P_ + pb * 80 + tid], psum[tid] * 0.5f * rsap);
    }
}

// ---------------- fallback fp32 fused GEMM+pool (used if ws too small) ------
__global__ __launch_bounds__(256) void main_kernel(const float* __restrict__ x,
                                                   const int* __restrict__ length,
                                                   const float* __restrict__ ws,
                                                   float* __restrict__ pes) {
    __shared__ float xs[N_][STRIDE_ + 1];
    __shared__ float rnorm[STRIDE_];
    __shared__ float poolp[P_][5];
    __shared__ float pooln[P_][5];

    int w = blockIdx.x;
    int b = blockIdx.y;
    const float* xb = x + (size_t)b * N_ * T_ + (size_t)w * STRIDE_;

    for (int i = threadIdx.x; i < N_ * STRIDE_; i += 256) {
        int n = i / STRIDE_;
        int t = i - n * STRIDE_;
        xs[n][t] = xb[n * T_ + t];
    }
    __syncthreads();

    if (threadIdx.x < STRIDE_) {
        float ssf = 0.0f;
        for (int n = 0; n < N_; n++) { float vv = xs[n][threadIdx.x]; ssf += vv * vv; }
        rnorm[threadIdx.x] = 1.0f / sqrtf(ssf + EPS_);
    }
    __syncthreads();

    int pt = threadIdx.x % 50;
    int tt = threadIdx.x / 50;

    if (tt < 5) {
        float acc[8][5];
#pragma unroll
        for (int i = 0; i < 8; i++)
#pragma unroll
            for (int j = 0; j < 5; j++) acc[i][j] = 0.0f;

        const float4* np4 = (const float4*)(ws + OFF_NPATT);
        int pbq = pt * 2;
        for (int n = 0; n < N_; n++) {
            float4 q0 = np4[n * (P_ / 4) + pbq];
            float4 q1 = np4[n * (P_ / 4) + pbq + 1];
            float qa[8] = { q0.x, q0.y, q0.z, q0.w, q1.x, q1.y, q1.z, q1.w };
            float xv0 = xs[n][tt * 5 + 0];
            float xv1 = xs[n][tt * 5 + 1];
            float xv2 = xs[n][tt * 5 + 2];
            float xv3 = xs[n][tt * 5 + 3];
            float xv4 = xs[n][tt * 5 + 4];
#pragma unroll
            for (int i = 0; i < 8; i++) {
                acc[i][0] += qa[i] * xv0;
                acc[i][1] += qa[i] * xv1;
                acc[i][2] += qa[i] * xv2;
                acc[i][3] += qa[i] * xv3;
                acc[i][4] += qa[i] * xv4;
            }
        }
#pragma unroll
        for (int i = 0; i < 8; i++) {
            float pm = -1e30f, nm = -1e30f;
#pragma unroll
            for (int j = 0; j < 5; j++) {
                float s = acc[i][j] * rnorm[tt * 5 + j];
                pm = fmaxf(pm, s);
                nm = fmaxf(nm, -s);
            }
            poolp[pt * 8 + i][tt] = pm;
            pooln[pt * 8 + i][tt] = nm;
        }
    }
    __syncthreads();

    float rsap = 1.0f / (float)(length[b] / STRIDE_);
    for (int p = threadIdx.x; p < P_; p += 256) {
        float pm = poolp[p][0], nm = pooln[p][0];
#pragma unroll
        for (int q = 1; q < 5; q++) {
            pm = fmaxf(pm, poolp[p][q]);
            nm = fmaxf(nm, pooln[p][q]);
        }
        atomicAdd(&pes[b * P_ + p], (pm + nm) * 0.5f * rsap);
    }
}

// ---------------- sparse graphs assembly + scalar outputs -------------------
__global__ __launch_bounds__(256) void graphs_kernel(const float* __restrict__ ws,
                                                     float* __restrict__ out) {
    int idx = blockIdx.x * 256 + threadIdx.x;
    if (idx == 0) {
        out[(size_t)B_ * N_ * N_] = ws[OFF_NORM];
        out[(size_t)B_ * N_ * N_ + 1] = ws[OFF_ORTH];
    }
    if (idx >= B_ * P_) return;
    int b = idx / P_;
    int p = idx - b * P_;

    float e = ws[OFF_PES + b * P_ + p];
    const float* keyval = ws + OFF_KEYVAL;
    const int* keyidx = (const int*)(ws + OFF_KEYIDX);
    float va[3] = { keyval[p * 4 + 0], keyval[p * 4 + 1], keyval[p * 4 + 2] };
    int ia[3] = { keyidx[p * 4 + 0], keyidx[p * 4 + 1], keyidx[p * 4 + 2] };

    float* g = out + (size_t)b * N_ * N_;
#pragma unroll
    for (int a = 0; a < 3; a++) {
#pragma unroll
        for (int c = 0; c < 3; c++) {
            float scale = (ia[a] == ia[c]) ? 1.0f : 6.0f;
            atomicAdd(&g[ia[a] * N_ + ia[c]], va[a] * va[c] * e * scale);
        }
    }
}

extern "C" void kernel_launch(void* const* d_in, const int* in_sizes, int n_in,
                              void* d_out, int out_size, void* d_ws, size_t ws_size,
                              hipStream_t stream) {
    const float* x = (const float*)d_in[0];
    const float* patterns = (const float*)d_in[1];
    const int* length = (const int*)d_in[2];
    float* out = (float*)d_out;
    float* ws = (float*)d_ws;

    hipMemsetAsync(ws + OFF_PES, 0, (size_t)(B_ * P_ + 2) * sizeof(float), stream);
    hipMemsetAsync(d_out, 0, (size_t)B_ * N_ * N_ * sizeof(float), stream);

    pat_kernel<<<P_, 64, 0, stream>>>(patterns, ws);
    orth_kernel<<<P_, 256, 0, stream>>>(ws);

    if (ws_size >= (size_t)WS_FAST_FLOATS * sizeof(float)) {
        tnorm_kernel<<<dim3((T_ + 63) / 64, B_), 256, 0, stream>>>(x, ws);
        gemm_kernel<<<dim3(5, 3, B_), 320, 0, stream>>>(ws, length, ws + OFF_PES);
    } else {
        main_kernel<<<dim3(T_ / STRIDE_, B_), 256, 0, stream>>>(x, length, ws, ws + OFF_PES);
    }
    graphs_kernel<<<(B_ * P_ + 255) / 256, 256, 0, stream>>>(ws, out);
}